// Round 1
// baseline (972.152 us; speedup 1.0000x reference)
//
#include <hip/hip_runtime.h>

// NCA update step: perceive (ident + sobel-x + sobel-y per channel) ->
// 48->128 relu -> 128->16 -> x_new = x + dx*fire -> alive masking
// (pre & post 3x3 wrap max-pool of alpha > 0.1).
//
// B=32, C=16, H=W=256, HIDDEN=128.  fp32 throughout (no fp32 MFMA on CDNA4,
// so the MLP runs on the vector ALU; weights stream through the scalar pipe).

#define CCH 16
#define HID 128
#define HH 256
#define WW 256
#define BB 32

// ---------------------------------------------------------------- kernel 0
// Transpose w2 (C x HID) -> w2t (HID x C) so the o-loop reads 16 contiguous
// floats (one 64B scalar load) per hidden unit.
__global__ __launch_bounds__(256) void w2_transpose_kernel(
    const float* __restrict__ w2, float* __restrict__ w2t) {
  const int i = blockIdx.x * 256 + threadIdx.x;
  if (i < CCH * HID) {
    const int c = i / HID;
    const int o = i - c * HID;
    w2t[o * CCH + c] = w2[i];
  }
}

// ---------------------------------------------------------------- kernel 1
// One block per (b, h) row; one thread per pixel. LDS holds 3 wrapped rows
// of all 16 channels (48 KB). Computes x_new, writes it to out, and stores
// alpha_new + pre_life planes for the second pass.
__global__ __launch_bounds__(256, 2) void nca_update_kernel(
    const float* __restrict__ x,
    const float* __restrict__ w1,
    const float* __restrict__ b1,
    const float* __restrict__ w2t,
    const float* __restrict__ b2,
    const int* __restrict__ fire,
    float* __restrict__ out,
    float* __restrict__ alpha_ws,
    unsigned char* __restrict__ pre_ws) {
  __shared__ float lds[3][CCH][WW];

  const int bh = blockIdx.x;
  const int b = bh >> 8;
  const int h = bh & 255;
  const int w = threadIdx.x;
  const int hm = (h + 255) & 255;
  const int hp = (h + 1) & 255;

  // Cooperative staging: 3 rows x 16 ch x 256 px, float4-vectorized,
  // fully coalesced (each (r,c) row is 256 contiguous floats).
  {
    const float* xb = x + (size_t)b * CCH * HH * WW;
    for (int i = threadIdx.x; i < 3 * CCH * (WW / 4); i += 256) {
      const int r = i >> 10;          // / (16*64)
      const int c = (i >> 6) & 15;
      const int w4 = i & 63;
      const int hr = (r == 0) ? hm : ((r == 1) ? h : hp);
      const float4 v = *reinterpret_cast<const float4*>(
          xb + ((size_t)c * HH + hr) * WW + w4 * 4);
      *reinterpret_cast<float4*>(&lds[r][c][w4 * 4]) = v;
    }
  }
  __syncthreads();

  const int wm = (w + 255) & 255;
  const int wp = (w + 1) & 255;

  // Perception: y[3c]=ident, y[3c+1]=sobel_x, y[3c+2]=sobel_y
  // (cross-correlation, matching lax.conv semantics).
  float y[3 * CCH];
#pragma unroll
  for (int c = 0; c < CCH; ++c) {
    const float tl = lds[0][c][wm], tc = lds[0][c][w], tr = lds[0][c][wp];
    const float ml = lds[1][c][wm], mc = lds[1][c][w], mr = lds[1][c][wp];
    const float bl = lds[2][c][wm], bc = lds[2][c][w], br = lds[2][c][wp];
    y[3 * c + 0] = mc;
    y[3 * c + 1] = 0.125f * (tr - tl) + 0.25f * (mr - ml) + 0.125f * (br - bl);
    y[3 * c + 2] = 0.125f * (bl - tl) + 0.25f * (bc - tc) + 0.125f * (br - tr);
  }

  // Pre-life: 3x3 wrap max-pool of alpha (channel 3) on the OLD x.
  float amax = lds[0][3][wm];
  amax = fmaxf(amax, lds[0][3][w]);
  amax = fmaxf(amax, lds[0][3][wp]);
  amax = fmaxf(amax, lds[1][3][wm]);
  amax = fmaxf(amax, lds[1][3][w]);
  amax = fmaxf(amax, lds[1][3][wp]);
  amax = fmaxf(amax, lds[2][3][wm]);
  amax = fmaxf(amax, lds[2][3][w]);
  amax = fmaxf(amax, lds[2][3][wp]);
  const bool pre = amax > 0.1f;

  // MLP: h_o = relu(w1[o,:] . y + b1[o]);  dx_c = sum_o w2t[o,c]*h_o + b2_c.
  // Weight reads are wave-uniform -> scalar loads (constant cache), keeping
  // the VALU free for pure FMA. 4 split accumulators break the 48-term
  // dependency chain.
  float acc[CCH];
#pragma unroll
  for (int c = 0; c < CCH; ++c) acc[c] = b2[c];

  for (int o = 0; o < HID; ++o) {
    const float* wr = w1 + o * 48;
    float h0 = 0.f, h1 = 0.f, h2 = 0.f, h3 = 0.f;
#pragma unroll
    for (int k = 0; k < 48; k += 4) {
      h0 = fmaf(wr[k + 0], y[k + 0], h0);
      h1 = fmaf(wr[k + 1], y[k + 1], h1);
      h2 = fmaf(wr[k + 2], y[k + 2], h2);
      h3 = fmaf(wr[k + 3], y[k + 3], h3);
    }
    float hv = ((h0 + h1) + (h2 + h3)) + b1[o];
    hv = fmaxf(hv, 0.0f);
    const float* w2r = w2t + o * CCH;
#pragma unroll
    for (int c = 0; c < CCH; ++c) acc[c] = fmaf(w2r[c], hv, acc[c]);
  }

  const size_t pix = ((size_t)b * HH + h) * WW + w;
  const float ff = (float)fire[pix];

#pragma unroll
  for (int c = 0; c < CCH; ++c) {
    const float v = lds[1][c][w] + acc[c] * ff;  // STEP_SIZE = 1
    out[((size_t)(b * CCH + c) * HH + h) * WW + w] = v;
    if (c == 3) alpha_ws[pix] = v;
  }
  pre_ws[pix] = pre ? (unsigned char)1 : (unsigned char)0;
}

// ---------------------------------------------------------------- kernel 2
// post_life = 3x3 wrap max-pool of alpha_new > 0.1; life = pre & post.
// out already holds x_new; only dead pixels need zeroing (writes are rare).
__global__ __launch_bounds__(256) void life_mask_kernel(
    const float* __restrict__ alpha_ws,
    const unsigned char* __restrict__ pre_ws,
    float* __restrict__ out) {
  const int bh = blockIdx.x;
  const int b = bh >> 8;
  const int h = bh & 255;
  const int w = threadIdx.x;
  const int hm = (h + 255) & 255;
  const int hp = (h + 1) & 255;
  const int wm = (w + 255) & 255;
  const int wp = (w + 1) & 255;

  const float* ab = alpha_ws + (size_t)b * HH * WW;
  float m = ab[(size_t)hm * WW + wm];
  m = fmaxf(m, ab[(size_t)hm * WW + w]);
  m = fmaxf(m, ab[(size_t)hm * WW + wp]);
  m = fmaxf(m, ab[(size_t)h * WW + wm]);
  m = fmaxf(m, ab[(size_t)h * WW + w]);
  m = fmaxf(m, ab[(size_t)h * WW + wp]);
  m = fmaxf(m, ab[(size_t)hp * WW + wm]);
  m = fmaxf(m, ab[(size_t)hp * WW + w]);
  m = fmaxf(m, ab[(size_t)hp * WW + wp]);

  const size_t pix = ((size_t)b * HH + h) * WW + w;
  const bool post = m > 0.1f;
  const bool pre = pre_ws[pix] != 0;
  if (!(pre && post)) {
#pragma unroll
    for (int c = 0; c < CCH; ++c)
      out[((size_t)(b * CCH + c) * HH + h) * WW + w] = 0.0f;
  }
}

// ---------------------------------------------------------------- launch
extern "C" void kernel_launch(void* const* d_in, const int* in_sizes, int n_in,
                              void* d_out, int out_size, void* d_ws,
                              size_t ws_size, hipStream_t stream) {
  const float* x = (const float*)d_in[0];
  const float* w1 = (const float*)d_in[1];
  const float* b1 = (const float*)d_in[2];
  const float* w2 = (const float*)d_in[3];
  const float* b2 = (const float*)d_in[4];
  const int* fire = (const int*)d_in[5];
  float* out = (float*)d_out;

  const size_t npix = (size_t)BB * HH * WW;  // 2,097,152
  // ws layout: [alpha_new: npix f32][pre_life: npix u8][w2t: 128*16 f32]
  float* alpha_ws = (float*)d_ws;
  unsigned char* pre_ws = (unsigned char*)d_ws + npix * sizeof(float);
  float* w2t =
      (float*)((unsigned char*)d_ws + npix * sizeof(float) + npix);

  w2_transpose_kernel<<<(CCH * HID + 255) / 256, 256, 0, stream>>>(w2, w2t);
  nca_update_kernel<<<BB * HH, 256, 0, stream>>>(x, w1, b1, w2t, b2, fire, out,
                                                 alpha_ws, pre_ws);
  life_mask_kernel<<<BB * HH, 256, 0, stream>>>(alpha_ws, pre_ws, out);
}

// Round 2
// 213.237 us; speedup vs baseline: 4.5590x; 4.5590x over previous
//
#include <hip/hip_runtime.h>

// NCA update via split-bf16 (bf16x3) MFMA.
// L1: H[128 x pix] = relu(W1[128x48] . Y[48 x pix] + b1)
// L2: DX[16 x pix] = W2[16x128] . H + b2 ; out = (x + DX*fire) * life
// W and Y are split hi/lo bf16; passes hh+hl+lh accumulated in fp32 MFMA
// (error ~2^-18), H stored as single bf16 (error ~2e-3 absolute in dx).

#define CCH 16
#define HID 128
#define HH 256
#define WW 256
#define BB 32

typedef __attribute__((ext_vector_type(8))) short bf16x8;
typedef __attribute__((ext_vector_type(4))) float f32x4;

__device__ inline unsigned short f2bf(float f) {  // round-to-nearest-even
  unsigned int u = __float_as_uint(f);
  u += 0x7FFFu + ((u >> 16) & 1u);
  return (unsigned short)(u >> 16);
}
__device__ inline float bf2f(unsigned short s) {
  return __uint_as_float(((unsigned int)s) << 16);
}

// ---------------------------------------------------------------- prep
// Pack W1 (128x48 f32) into A-fragment order for mfma_f32_16x16x32_bf16,
// K padded to 64 with ZEROS (so uninitialized Y rows 48..63 contribute 0).
// Layout: w1p[(((plane*2 + kstep)*8 + mtile)*64 + lane)*8 + j], plane 0=hi 1=lo.
// A-frag mapping: row = mtile*16 + (lane&15), k = kstep*32 + (lane>>4)*8 + j.
__global__ __launch_bounds__(256) void pack_w1_kernel(
    const float* __restrict__ w1, unsigned short* __restrict__ w1p) {
  const int tid = blockIdx.x * 256 + threadIdx.x;
  if (tid >= 2048) return;
  const int l = tid & 63, m = (tid >> 6) & 7, ks = (tid >> 9) & 1,
            pl = (tid >> 10) & 1;
  const int row = m * 16 + (l & 15);
  const int kb = ks * 32 + (l >> 4) * 8;
  const size_t off = ((((size_t)pl * 2 + ks) * 8 + m) * 64 + l) * 8;
#pragma unroll
  for (int j = 0; j < 8; ++j) {
    const int k = kb + j;
    const float v = (k < 48) ? w1[row * 48 + k] : 0.0f;
    const unsigned short hi = f2bf(v);
    w1p[off + j] = (pl == 0) ? hi : f2bf(v - bf2f(hi));
  }
}

// Pack W2 (16x128 f32): w2p[(((pl*4 + ks)*64 + lane)*8 + j)],
// row = lane&15, k = ks*32 + (lane>>4)*8 + j.
__global__ __launch_bounds__(256) void pack_w2_kernel(
    const float* __restrict__ w2, unsigned short* __restrict__ w2p) {
  const int tid = blockIdx.x * 256 + threadIdx.x;
  if (tid >= 512) return;
  const int l = tid & 63, ks = (tid >> 6) & 3, pl = (tid >> 8) & 1;
  const int row = l & 15;
  const int kb = ks * 32 + (l >> 4) * 8;
  const size_t off = (((size_t)pl * 4 + ks) * 64 + l) * 8;
#pragma unroll
  for (int j = 0; j < 8; ++j) {
    const float v = w2[row * 128 + kb + j];
    const unsigned short hi = f2bf(v);
    w2p[off + j] = (pl == 0) ? hi : f2bf(v - bf2f(hi));
  }
}

// ---------------------------------------------------------------- main
// One block = 128 pixels (half of one image row). 256 threads = 4 waves.
// LDS: Y hi/lo [128 px][72 rows] bf16 (36864 B), later reused for
// H [128 px][136 rows] bf16 (34816 B).
__global__ __launch_bounds__(256) void nca_mfma_kernel(
    const float* __restrict__ x, const float* __restrict__ b1,
    const float* __restrict__ b2, const unsigned short* __restrict__ w1p,
    const unsigned short* __restrict__ w2p, const int* __restrict__ fire,
    float* __restrict__ out, float* __restrict__ alpha_ws,
    unsigned char* __restrict__ pre_ws) {
  __shared__ __align__(16) unsigned short smem[2 * 128 * 72];
  unsigned short* Yh = smem;
  unsigned short* Yl = smem + 128 * 72;
  unsigned short* Hs = smem;  // reused after L1 completes

  const int bid = blockIdx.x;
  const int b = bid >> 9;
  const int h = (bid >> 1) & 255;
  const int wt = bid & 1;
  const int tid = threadIdx.x;
  const int wv = tid >> 6, lane = tid & 63, g = lane >> 4, ln = lane & 15;

  // ---- phase 1: perception -> Y (split bf16, B-operand layout [px][k])
  {
    const int p = tid & 127;          // pixel within tile
    const int c0 = (tid >> 7) * 8;    // channel half: 0..7 or 8..15
    const int wg = wt * 128 + p;
    const int wm = (wg + 255) & 255, wpp = (wg + 1) & 255;
    const int hm = (h + 255) & 255, hp = (h + 1) & 255;
    unsigned short ybh[24], ybl[24];
    float amax = -1e30f;
#pragma unroll
    for (int ci = 0; ci < 8; ++ci) {
      const int c = c0 + ci;
      const float* xc = x + (size_t)(b * CCH + c) * HH * WW;
      const float tl = xc[hm * WW + wm], tc_ = xc[hm * WW + wg],
                  tr = xc[hm * WW + wpp];
      const float ml = xc[h * WW + wm], mc = xc[h * WW + wg],
                  mr = xc[h * WW + wpp];
      const float bl = xc[hp * WW + wm], bc = xc[hp * WW + wg],
                  br = xc[hp * WW + wpp];
      const float y0 = mc;
      const float y1 =
          0.125f * (tr - tl) + 0.25f * (mr - ml) + 0.125f * (br - bl);
      const float y2 =
          0.125f * (bl - tl) + 0.25f * (bc - tc_) + 0.125f * (br - tr);
      float yv[3] = {y0, y1, y2};
#pragma unroll
      for (int d = 0; d < 3; ++d) {
        const unsigned short hi = f2bf(yv[d]);
        ybh[ci * 3 + d] = hi;
        ybl[ci * 3 + d] = f2bf(yv[d] - bf2f(hi));
      }
      if (c == 3) {
        float m1 = fmaxf(fmaxf(tl, tc_), tr);
        float m2 = fmaxf(fmaxf(ml, mc), mr);
        float m3 = fmaxf(fmaxf(bl, bc), br);
        amax = fmaxf(fmaxf(m1, m2), m3);
      }
    }
    const int ybase = p * 72 + c0 * 3;
#pragma unroll
    for (int i = 0; i < 3; ++i) {
      bf16x8 vh, vl;
#pragma unroll
      for (int j = 0; j < 8; ++j) {
        vh[j] = (short)ybh[i * 8 + j];
        vl[j] = (short)ybl[i * 8 + j];
      }
      *(bf16x8*)&Yh[ybase + i * 8] = vh;
      *(bf16x8*)&Yl[ybase + i * 8] = vl;
    }
    if (c0 == 8) {  // rows 48..63: values never matter (W1 cols zeroed),
                    // but must not be NaN bit patterns -> zero them.
      bf16x8 z;
#pragma unroll
      for (int j = 0; j < 8; ++j) z[j] = 0;
      *(bf16x8*)&Yh[p * 72 + 48] = z;
      *(bf16x8*)&Yh[p * 72 + 56] = z;
      *(bf16x8*)&Yl[p * 72 + 48] = z;
      *(bf16x8*)&Yl[p * 72 + 56] = z;
    } else {
      const size_t pix = ((size_t)b * HH + h) * WW + wg;
      pre_ws[pix] = (amax > 0.1f) ? 1 : 0;
    }
  }
  __syncthreads();

  // ---- phase 2: L1 GEMM. Wave wv owns M-tiles {2wv, 2wv+1}.
  bf16x8 A1[2][4];  // [mi][ hi-k0, hi-k1, lo-k0, lo-k1 ]
#pragma unroll
  for (int mi = 0; mi < 2; ++mi) {
    const int m = wv * 2 + mi;
    A1[mi][0] = *(const bf16x8*)(w1p + ((size_t)((0 * 2 + 0) * 8 + m) * 64 + lane) * 8);
    A1[mi][1] = *(const bf16x8*)(w1p + ((size_t)((0 * 2 + 1) * 8 + m) * 64 + lane) * 8);
    A1[mi][2] = *(const bf16x8*)(w1p + ((size_t)((1 * 2 + 0) * 8 + m) * 64 + lane) * 8);
    A1[mi][3] = *(const bf16x8*)(w1p + ((size_t)((1 * 2 + 1) * 8 + m) * 64 + lane) * 8);
  }
  f32x4 acc[2][8];
#pragma unroll
  for (int mi = 0; mi < 2; ++mi)
#pragma unroll
    for (int nt = 0; nt < 8; ++nt) acc[mi][nt] = (f32x4){0.f, 0.f, 0.f, 0.f};

  for (int nt = 0; nt < 8; ++nt) {
    const int yb = (nt * 16 + ln) * 72 + g * 8;
    const bf16x8 Bh0 = *(const bf16x8*)&Yh[yb];
    const bf16x8 Bh1 = *(const bf16x8*)&Yh[yb + 32];
    const bf16x8 Bl0 = *(const bf16x8*)&Yl[yb];
    const bf16x8 Bl1 = *(const bf16x8*)&Yl[yb + 32];
#pragma unroll
    for (int mi = 0; mi < 2; ++mi) {
      f32x4 a = acc[mi][nt];
      a = __builtin_amdgcn_mfma_f32_16x16x32_bf16(A1[mi][0], Bh0, a, 0, 0, 0);
      a = __builtin_amdgcn_mfma_f32_16x16x32_bf16(A1[mi][1], Bh1, a, 0, 0, 0);
      a = __builtin_amdgcn_mfma_f32_16x16x32_bf16(A1[mi][0], Bl0, a, 0, 0, 0);
      a = __builtin_amdgcn_mfma_f32_16x16x32_bf16(A1[mi][1], Bl1, a, 0, 0, 0);
      a = __builtin_amdgcn_mfma_f32_16x16x32_bf16(A1[mi][2], Bh0, a, 0, 0, 0);
      a = __builtin_amdgcn_mfma_f32_16x16x32_bf16(A1[mi][3], Bh1, a, 0, 0, 0);
      acc[mi][nt] = a;
    }
  }
  __syncthreads();  // all Y reads done; smem may be reused for H

  // ---- phase 3: bias + relu -> H bf16 in LDS [px][136]
#pragma unroll
  for (int mi = 0; mi < 2; ++mi) {
    const int m = wv * 2 + mi;
    const int hr0 = m * 16 + g * 4;
    const f32x4 b1v = *(const f32x4*)(b1 + hr0);
#pragma unroll
    for (int nt = 0; nt < 8; ++nt) {
      const int p = nt * 16 + ln;
      const float h0 = fmaxf(acc[mi][nt][0] + b1v[0], 0.f);
      const float h1 = fmaxf(acc[mi][nt][1] + b1v[1], 0.f);
      const float h2 = fmaxf(acc[mi][nt][2] + b1v[2], 0.f);
      const float h3 = fmaxf(acc[mi][nt][3] + b1v[3], 0.f);
      unsigned int* dst = (unsigned int*)&Hs[p * 136 + hr0];
      dst[0] = (unsigned int)f2bf(h0) | ((unsigned int)f2bf(h1) << 16);
      dst[1] = (unsigned int)f2bf(h2) | ((unsigned int)f2bf(h3) << 16);
    }
  }
  __syncthreads();

  // ---- phase 4: L2 GEMM. Wave wv owns pixel tiles {2wv, 2wv+1}.
  bf16x8 A2[8];  // [pl*4 + ks]
#pragma unroll
  for (int i = 0; i < 8; ++i)
    A2[i] = *(const bf16x8*)(w2p + ((size_t)i * 64 + lane) * 8);
  f32x4 dxa[2];
#pragma unroll
  for (int ni = 0; ni < 2; ++ni) {
    const int nt = wv * 2 + ni;
    const int hb = (nt * 16 + ln) * 136 + g * 8;
    f32x4 a = (f32x4){0.f, 0.f, 0.f, 0.f};
#pragma unroll
    for (int ks = 0; ks < 4; ++ks) {
      const bf16x8 Bh = *(const bf16x8*)&Hs[hb + ks * 32];
      a = __builtin_amdgcn_mfma_f32_16x16x32_bf16(A2[ks], Bh, a, 0, 0, 0);
      a = __builtin_amdgcn_mfma_f32_16x16x32_bf16(A2[4 + ks], Bh, a, 0, 0, 0);
    }
    dxa[ni] = a;
  }

  // ---- phase 5: epilogue. C-frag: pixel = lane&15, channel = g*4 + r.
  const f32x4 b2v = *(const f32x4*)(b2 + g * 4);
#pragma unroll
  for (int ni = 0; ni < 2; ++ni) {
    const int nt = wv * 2 + ni;
    const int wg = wt * 128 + nt * 16 + ln;
    const size_t pix = ((size_t)b * HH + h) * WW + wg;
    const float f = (float)fire[pix];
#pragma unroll
    for (int r = 0; r < 4; ++r) {
      const int c = g * 4 + r;
      const size_t xi = ((size_t)(b * CCH + c) * HH + h) * WW + wg;
      const float v = x[xi] + (dxa[ni][r] + b2v[r]) * f;
      out[xi] = v;
      if (c == 3) alpha_ws[pix] = v;
    }
  }
}

// ---------------------------------------------------------------- life
__global__ __launch_bounds__(256) void life_mask_kernel(
    const float* __restrict__ alpha_ws, const unsigned char* __restrict__ pre_ws,
    float* __restrict__ out) {
  const int bh = blockIdx.x;
  const int b = bh >> 8;
  const int h = bh & 255;
  const int w = threadIdx.x;
  const int hm = (h + 255) & 255;
  const int hp = (h + 1) & 255;
  const int wm = (w + 255) & 255;
  const int wp = (w + 1) & 255;

  const float* ab = alpha_ws + (size_t)b * HH * WW;
  float m = ab[(size_t)hm * WW + wm];
  m = fmaxf(m, ab[(size_t)hm * WW + w]);
  m = fmaxf(m, ab[(size_t)hm * WW + wp]);
  m = fmaxf(m, ab[(size_t)h * WW + wm]);
  m = fmaxf(m, ab[(size_t)h * WW + w]);
  m = fmaxf(m, ab[(size_t)h * WW + wp]);
  m = fmaxf(m, ab[(size_t)hp * WW + wm]);
  m = fmaxf(m, ab[(size_t)hp * WW + w]);
  m = fmaxf(m, ab[(size_t)hp * WW + wp]);

  const size_t pix = ((size_t)b * HH + h) * WW + w;
  const bool post = m > 0.1f;
  const bool pre = pre_ws[pix] != 0;
  if (!(pre && post)) {
#pragma unroll
    for (int c = 0; c < CCH; ++c)
      out[((size_t)(b * CCH + c) * HH + h) * WW + w] = 0.0f;
  }
}

// ---------------------------------------------------------------- launch
extern "C" void kernel_launch(void* const* d_in, const int* in_sizes, int n_in,
                              void* d_out, int out_size, void* d_ws,
                              size_t ws_size, hipStream_t stream) {
  const float* x = (const float*)d_in[0];
  const float* w1 = (const float*)d_in[1];
  const float* b1 = (const float*)d_in[2];
  const float* w2 = (const float*)d_in[3];
  const float* b2 = (const float*)d_in[4];
  const int* fire = (const int*)d_in[5];
  float* out = (float*)d_out;

  const size_t npix = (size_t)BB * HH * WW;  // 2,097,152
  // ws: [w1p 32KB][w2p 8KB][alpha npix f32][pre npix u8]
  unsigned short* w1p = (unsigned short*)d_ws;
  unsigned short* w2p = (unsigned short*)((char*)d_ws + 32768);
  float* alpha_ws = (float*)((char*)d_ws + 40960);
  unsigned char* pre_ws = (unsigned char*)d_ws + 40960 + npix * sizeof(float);

  pack_w1_kernel<<<8, 256, 0, stream>>>(w1, w1p);
  pack_w2_kernel<<<2, 256, 0, stream>>>(w2, w2p);
  nca_mfma_kernel<<<BB * HH * 2, 256, 0, stream>>>(x, b1, b2, w1p, w2p, fire,
                                                   out, alpha_ws, pre_ws);
  life_mask_kernel<<<BB * HH, 256, 0, stream>>>(alpha_ws, pre_ws, out);
}